// Round 15
// baseline (349.470 us; speedup 1.0000x reference)
//
#include <hip/hip_runtime.h>
#include <hip/hip_bf16.h>
#include <stdint.h>

// y[b,s,o] = sum_k x[b,s,k] * W[o,k] + bias[o]
// W from packed FP4 (E2M1 nibbles in int32 bytes) * per-32 fp32 scales.
// M = 8192, N = 4096, K = 4096.
// r15 = r14 + double-buffered B fragments: LDB moved to P3/P7 (one phase
// before first use, under certified buffers), LGKM4 waits removed. B-read
// bursts now drain under a full MFMA phase instead of stalling at P0/P4.
// Barriers / vmcnt / staging slots IDENTICAL to r9/r14 (verified schedule).

#define M_DIM 8192
#define N_DIM 4096
#define K_DIM 4096

typedef __bf16 bf16x8 __attribute__((ext_vector_type(8)));
typedef float  f32x4  __attribute__((ext_vector_type(4)));
typedef int    i32x4  __attribute__((ext_vector_type(4)));
typedef float  f32x4v __attribute__((ext_vector_type(4)));

// ---------------- helpers ----------------

__device__ __forceinline__ uint16_t f32_to_bf16_rn(float f) {
  uint32_t u = __float_as_uint(f);
  uint32_t r = (u + 0x7FFFu + ((u >> 16) & 1u)) >> 16;
  return (uint16_t)r;
}
__device__ __forceinline__ uint32_t pack_bf16x2(float e0, float e1) {
  return (uint32_t)f32_to_bf16_rn(e0) | ((uint32_t)f32_to_bf16_rn(e1) << 16);
}
__device__ __forceinline__ float fp4_to_f32(int nib) {
  uint32_t e = (uint32_t)(nib >> 1) & 3u;
  uint32_t m = (uint32_t)nib & 1u;
  uint32_t s = (uint32_t)(nib >> 3) & 1u;
  uint32_t bits = e ? (((126u + e) << 23) | (m << 22)) : (m ? 0x3F000000u : 0u);
  bits |= s << 31;
  return __uint_as_float(bits);
}
__device__ __forceinline__ void gload_lds16(const void* g, void* lds) {
  __builtin_amdgcn_global_load_lds(
      (const __attribute__((address_space(1))) unsigned int*)g,
      (__attribute__((address_space(3))) unsigned int*)lds,
      16, 0, 0);
}

// ---------------- merged pre-kernel: dequant W + cvt x ----------------
__global__ __launch_bounds__(256) void pre_all(const int* __restrict__ q,
                                               const float* __restrict__ scales,
                                               uint32_t* __restrict__ W,
                                               const float* __restrict__ x,
                                               uint32_t* __restrict__ xb) {
  const int bid = blockIdx.x;
  if (bid < 2048) {
    int b = bid * 256 + threadIdx.x;
    float sc = scales[b];
    const i32x4* q4 = reinterpret_cast<const i32x4*>(q) + (size_t)b * 4;
    i32x4* dst = reinterpret_cast<i32x4*>(W + (size_t)b * 16);
#pragma unroll
    for (int i = 0; i < 4; ++i) {
      i32x4 v = __builtin_nontemporal_load(q4 + i);
      int b0 = v[0] & 0xFF, b1 = v[1] & 0xFF, b2 = v[2] & 0xFF, b3 = v[3] & 0xFF;
      uint32_t p0 = pack_bf16x2(fp4_to_f32((b0 >> 4) & 15) * sc, fp4_to_f32(b0 & 15) * sc);
      uint32_t p1 = pack_bf16x2(fp4_to_f32((b1 >> 4) & 15) * sc, fp4_to_f32(b1 & 15) * sc);
      uint32_t p2 = pack_bf16x2(fp4_to_f32((b2 >> 4) & 15) * sc, fp4_to_f32(b2 & 15) * sc);
      uint32_t p3 = pack_bf16x2(fp4_to_f32((b3 >> 4) & 15) * sc, fp4_to_f32(b3 & 15) * sc);
      i32x4 o;
      o[0] = (int)p0; o[1] = (int)p1; o[2] = (int)p2; o[3] = (int)p3;
      dst[i] = o;
    }
  } else {
    size_t i = ((size_t)(bid - 2048) * 256 + threadIdx.x) * 8;
    f32x4v a = __builtin_nontemporal_load(reinterpret_cast<const f32x4v*>(x + i));
    f32x4v c = __builtin_nontemporal_load(reinterpret_cast<const f32x4v*>(x + i + 4));
    i32x4 o;
    o[0] = (int)pack_bf16x2(a[0], a[1]);
    o[1] = (int)pack_bf16x2(a[2], a[3]);
    o[2] = (int)pack_bf16x2(c[0], c[1]);
    o[3] = (int)pack_bf16x2(c[2], c[3]);
    *reinterpret_cast<i32x4*>(xb + i / 2) = o;
  }
}

// ---------------- GEMM: 256x256 8-phase, persistent 2-tile blocks ----------
// r9 sync skeleton (8 barriers/pair; P0/P4 barriers REQUIRED — r8 race).
// B frags double-buffered: bset0 feeds even-K-tile phases (P0-P3), bset1
// feeds odd (P4-P7). LDB(BUF1,1)@P3 (BUF1 certified by VM4@P2+barrier);
// LDB(BUF0,0)@P7 (BUF0-next certified by VM6@P6+barrier). Register WARs
// same-wave in-order (set1: prev-P7 read < P3 write; set0: P3 read < P7).

#define BUF0 0
#define BUF1 65536
#define A0OFF 0
#define A1OFF 16384
#define B0OFF 32768
#define B1OFF 49152
#define AH1 (128 * 4096)       // +128 rows (elements)

#define BARRIER()   asm volatile("s_barrier" ::: "memory")
#define WAIT_LGKM0() do { asm volatile("s_waitcnt lgkmcnt(0)" ::: "memory"); \
                          __builtin_amdgcn_sched_barrier(0); } while (0)
#define WAIT_VM6()  asm volatile("s_waitcnt vmcnt(6)" ::: "memory")
#define WAIT_VM4()  asm volatile("s_waitcnt vmcnt(4)" ::: "memory")
#define WAIT_VM0()  asm volatile("s_waitcnt vmcnt(0)" ::: "memory")
#define PRIO1()     __builtin_amdgcn_s_setprio(1)
#define PRIO0()     __builtin_amdgcn_s_setprio(0)

#define LDA2(SET, CB, F) do {                                      \
    const uint32_t r0_ = a_rd + (F) * 2048;                        \
    const uint32_t r1_ = a_rd + ((F) + 1) * 2048;                  \
    aA[SET][0][0] = *(const bf16x8*)(smem + (CB) + r0_);           \
    aA[SET][0][1] = *(const bf16x8*)(smem + (CB) + (r0_ ^ 64));    \
    aA[SET][1][0] = *(const bf16x8*)(smem + (CB) + r1_);           \
    aA[SET][1][1] = *(const bf16x8*)(smem + (CB) + (r1_ ^ 64));    \
  } while (0)

// read all 4 B frags of buf CB into B-set BS
#define LDB(CB, BS) do {                                           \
    _Pragma("unroll")                                              \
    for (int nf_ = 0; nf_ < 4; ++nf_) {                            \
      const uint32_t r_ = b_rd + nf_ * 2048;                       \
      bfr[BS][nf_][0] = *(const bf16x8*)(smem + (CB) + r_);        \
      bfr[BS][nf_][1] = *(const bf16x8*)(smem + (CB) + (r_ ^ 64)); \
    }                                                              \
  } while (0)

#define MFMAQ(Q, SET, BS) do {                                     \
    _Pragma("unroll")                                              \
    for (int nf_ = 0; nf_ < 4; ++nf_) {                            \
      _Pragma("unroll")                                            \
      for (int kk_ = 0; kk_ < 2; ++kk_) {                          \
        acc[2*(Q)][nf_] = __builtin_amdgcn_mfma_f32_16x16x32_bf16( \
            aA[SET][0][kk_], bfr[BS][nf_][kk_], acc[2*(Q)][nf_], 0, 0, 0);   \
        acc[2*(Q)+1][nf_] = __builtin_amdgcn_mfma_f32_16x16x32_bf16(         \
            aA[SET][1][kk_], bfr[BS][nf_][kk_], acc[2*(Q)+1][nf_], 0, 0, 0); \
      }                                                            \
    }                                                              \
  } while (0)

__device__ __forceinline__ void stage_half_tile(const __bf16* gsrc, char* lds_dst) {
  gload_lds16(gsrc, lds_dst);
  gload_lds16(gsrc + 64 * 4096, lds_dst + 8192);
}

// steady-state K-tile pair (E in buf0/bset0, O in buf1/bset1)
#define MAIN_PAIR(GA, kO, kE2, kO2)                                     \
  do {                                                                  \
    /* P0 */                                                            \
    WAIT_LGKM0(); LDA2(1, BUF0, 2);                                     \
    PRIO1(); MFMAQ(0, 0, 0); PRIO0();                                   \
    stage_half_tile((GA) + AH1 + (kO), stw + BUF1 + A1OFF);             \
    BARRIER();                                                          \
    /* P1 */                                                            \
    WAIT_LGKM0(); LDA2(0, BUF0, 4);                                     \
    PRIO1(); MFMAQ(1, 1, 0); PRIO0();                                   \
    stage_half_tile(gB + (kE2), stw + BUF0 + B0OFF);                    \
    BARRIER();                                                          \
    /* P2 */                                                            \
    WAIT_LGKM0(); LDA2(1, BUF0, 6);                                     \
    PRIO1(); MFMAQ(2, 0, 0); PRIO0();                                   \
    stage_half_tile(gB + AH1 + (kE2), stw + BUF0 + B1OFF);              \
    WAIT_VM4();                                                         \
    BARRIER();                                                          \
    /* P3 */                                                            \
    WAIT_LGKM0(); LDB(BUF1, 1); LDA2(0, BUF1, 0);                       \
    PRIO1(); MFMAQ(3, 1, 0); PRIO0();                                   \
    stage_half_tile((GA) + (kE2), stw + BUF0 + A0OFF);                  \
    BARRIER();                                                          \
    /* P4 */                                                            \
    WAIT_LGKM0(); LDA2(1, BUF1, 2);                                     \
    PRIO1(); MFMAQ(0, 0, 1); PRIO0();                                   \
    stage_half_tile((GA) + AH1 + (kE2), stw + BUF0 + A1OFF);            \
    BARRIER();                                                          \
    /* P5 */                                                            \
    WAIT_LGKM0(); LDA2(0, BUF1, 4);                                     \
    PRIO1(); MFMAQ(1, 1, 1); PRIO0();                                   \
    stage_half_tile(gB + (kO2), stw + BUF1 + B0OFF);                    \
    BARRIER();                                                          \
    /* P6 */                                                            \
    WAIT_LGKM0(); LDA2(1, BUF1, 6);                                     \
    PRIO1(); MFMAQ(2, 0, 1); PRIO0();                                   \
    stage_half_tile(gB + AH1 + (kO2), stw + BUF1 + B1OFF);              \
    stage_half_tile((GA) + (kO2),     stw + BUF1 + A0OFF);              \
    WAIT_VM6();                                                         \
    BARRIER();                                                          \
    /* P7 */                                                            \
    WAIT_LGKM0(); LDB(BUF0, 0); LDA2(0, BUF0, 0);                       \
    PRIO1(); MFMAQ(3, 1, 1); PRIO0();                                   \
    BARRIER();                                                          \
  } while (0)

__global__ __launch_bounds__(512, 2) void gemm256_p2(const __bf16* __restrict__ A,
                                                     const __bf16* __restrict__ B,
                                                     const float* __restrict__ bias,
                                                     float* __restrict__ C) {
  __shared__ __align__(16) char smem[131072];

  const int t    = threadIdx.x;          // 0..511
  const int wave = t >> 6;               // 0..7
  const int lane = t & 63;
  const int l16  = lane & 15;
  const int kg   = lane >> 4;            // 0..3
  const int wm   = wave >> 2;            // 0..1 (M half)
  const int wn   = wave & 3;             // 0..3 (N quarter)

  // XCD-aware bijective block swizzle (nwg = 256 = 8 x 32)
  const int orig = blockIdx.x;
  const int swz  = (orig & 7) * 32 + (orig >> 3);
  const int bn   = swz & 15;             // 16 bn (fastest)
  const int bm   = swz >> 4;             // 0..15 (tile2 uses bm+16)

  // staging source (pre-swizzled): thread t covers row t>>3 (+s*64),
  // chunk c8 = (t&7) ^ ((t>>3)&7)
  const int c8 = (t & 7) ^ ((t >> 3) & 7);
  const __bf16* gA  = A + ((size_t)(bm * 256 + (t >> 3))) * 4096 + c8 * 8;
  const __bf16* gA2 = gA + (size_t)16 * 256 * 4096;
  const __bf16* gB  = B + ((size_t)(bn * 256 + (t >> 3))) * 4096 + c8 * 8;
  char* stw = smem + wave * 1024;        // + lane*16 implicit in gload_lds

  // ds_read byte offsets (3-bit row swizzle): row = frag*16 + l16,
  // chunk bits [6:4] = kg ^ (l16&7); kk half via ^64 at use site
  const uint32_t ca = ((uint32_t)(kg ^ (l16 & 7))) << 4;
  const uint32_t a_rd = (uint32_t)(wm ? A1OFF : A0OFF) + (uint32_t)l16 * 128 + ca;
  const uint32_t b_rd = (uint32_t)(wn >= 2 ? B1OFF : B0OFF) +
                        (uint32_t)(wn & 1) * 8192 + (uint32_t)l16 * 128 + ca;

  f32x4 acc[8][4];
#pragma unroll
  for (int i = 0; i < 8; ++i)
#pragma unroll
    for (int j = 0; j < 4; ++j) acc[i][j] = (f32x4){0.f, 0.f, 0.f, 0.f};

  bf16x8 aA[2][2][2];    // [set][frag][kk]
  bf16x8 bfr[2][4][2];   // [bset][nf][kk]

  // ---- prologue: tile0 K0 -> buf0 (8), K1 B + A0 -> buf1 (6)
  stage_half_tile(gA,            stw + BUF0 + A0OFF);
  stage_half_tile(gA + AH1,      stw + BUF0 + A1OFF);
  stage_half_tile(gB,            stw + BUF0 + B0OFF);
  stage_half_tile(gB + AH1,      stw + BUF0 + B1OFF);
  stage_half_tile(gB + 64,       stw + BUF1 + B0OFF);
  stage_half_tile(gB + AH1 + 64, stw + BUF1 + B1OFF);
  stage_half_tile(gA + 64,       stw + BUF1 + A0OFF);
  WAIT_VM6();
  BARRIER();
  LDB(BUF0, 0); LDA2(0, BUF0, 0);

  // ================= tile 1 (bm) =================
  for (int j = 0; j < 31; ++j) {
    const size_t kO  = (size_t)(2 * j + 1) * 64;
    const size_t kE2 = (size_t)(2 * j + 2) * 64;
    const size_t kO2 = (size_t)(2 * j + 3) * 64;
    MAIN_PAIR(gA, kO, kE2, kO2);
  }
  // ---- peel pair 31 (K62 buf0, K63 buf1) + stage tile2 K0/K1
  {
    const size_t kO = (size_t)63 * 64;
    WAIT_LGKM0(); LDA2(1, BUF0, 2);
    PRIO1(); MFMAQ(0, 0, 0); PRIO0();
    stage_half_tile(gA + AH1 + kO, stw + BUF1 + A1OFF);
    BARRIER();
    WAIT_LGKM0(); LDA2(0, BUF0, 4);
    PRIO1(); MFMAQ(1, 1, 0); PRIO0();
    stage_half_tile(gB, stw + BUF0 + B0OFF);            // B0(t2 K0)
    BARRIER();
    WAIT_LGKM0(); LDA2(1, BUF0, 6);
    PRIO1(); MFMAQ(2, 0, 0); PRIO0();
    stage_half_tile(gB + AH1, stw + BUF0 + B1OFF);      // B1(t2 K0)
    WAIT_VM4();            // certifies K63 -> buf1 fully landed
    BARRIER();
    WAIT_LGKM0(); LDB(BUF1, 1); LDA2(0, BUF1, 0);
    PRIO1(); MFMAQ(3, 1, 0); PRIO0();
    stage_half_tile(gA2, stw + BUF0 + A0OFF);           // A0(t2 K0)
    BARRIER();
    WAIT_LGKM0(); LDA2(1, BUF1, 2);
    PRIO1(); MFMAQ(0, 0, 1); PRIO0();
    stage_half_tile(gA2 + AH1, stw + BUF0 + A1OFF);     // A1(t2 K0)
    BARRIER();
    WAIT_LGKM0(); LDA2(0, BUF1, 4);
    PRIO1(); MFMAQ(1, 1, 1); PRIO0();
    stage_half_tile(gB + 64, stw + BUF1 + B0OFF);       // B0(t2 K1)
    BARRIER();
    WAIT_LGKM0(); LDA2(1, BUF1, 6);
    PRIO1(); MFMAQ(2, 0, 1); PRIO0();
    stage_half_tile(gB + AH1 + 64, stw + BUF1 + B1OFF); // B1(t2 K1)
    BARRIER();
    WAIT_LGKM0();
    PRIO1(); MFMAQ(3, 1, 1); PRIO0();
    stage_half_tile(gA2 + 64, stw + BUF1 + A0OFF);      // A0(t2 K1)
    WAIT_VM0();            // tile2 K0 + staged K1 parts landed
    BARRIER();
  }
  // ---- epilogue tile1: issue stores (drain under tile2 compute)
#pragma unroll
  for (int mf = 0; mf < 8; ++mf) {
    const int m0 = bm * 256 + wm * 128 + mf * 16 + kg * 4;
#pragma unroll
    for (int nf = 0; nf < 4; ++nf) {
      const int n = bn * 256 + wn * 64 + nf * 16 + l16;
      const float bv = bias[n];
#pragma unroll
      for (int r = 0; r < 4; ++r)
        C[(size_t)(m0 + r) * N_DIM + n] = acc[mf][nf][r] + bv;
    }
  }
#pragma unroll
  for (int i = 0; i < 8; ++i)
#pragma unroll
    for (int j = 0; j < 4; ++j) acc[i][j] = (f32x4){0.f, 0.f, 0.f, 0.f};
  LDB(BUF0, 0); LDA2(0, BUF0, 0);   // tile2 K0 (certified by VM0 above)

  // ================= tile 2 (bm + 16) =================
  for (int j = 0; j < 31; ++j) {
    const size_t kO  = (size_t)(2 * j + 1) * 64;
    const size_t kE2 = (size_t)(2 * j + 2) * 64;
    const size_t kO2 = (size_t)(2 * j + 3) * 64;
    MAIN_PAIR(gA2, kO, kE2, kO2);
  }
  // ---- peel pair 31 (no further stages)
  {
    const size_t kO = (size_t)63 * 64;
    WAIT_LGKM0(); LDA2(1, BUF0, 2);
    PRIO1(); MFMAQ(0, 0, 0); PRIO0();
    stage_half_tile(gA2 + AH1 + kO, stw + BUF1 + A1OFF);
    BARRIER();
    WAIT_LGKM0(); LDA2(0, BUF0, 4);
    PRIO1(); MFMAQ(1, 1, 0); PRIO0();
    BARRIER();
    WAIT_LGKM0(); LDA2(1, BUF0, 6);
    PRIO1(); MFMAQ(2, 0, 0); PRIO0();
    WAIT_VM0();
    BARRIER();
    WAIT_LGKM0(); LDB(BUF1, 1); LDA2(0, BUF1, 0);
    PRIO1(); MFMAQ(3, 1, 0); PRIO0();
    BARRIER();
    WAIT_LGKM0(); LDA2(1, BUF1, 2);
    PRIO1(); MFMAQ(0, 0, 1); PRIO0();
    BARRIER();
    WAIT_LGKM0(); LDA2(0, BUF1, 4);
    PRIO1(); MFMAQ(1, 1, 1); PRIO0();
    BARRIER();
    WAIT_LGKM0(); LDA2(1, BUF1, 6);
    PRIO1(); MFMAQ(2, 0, 1); PRIO0();
    BARRIER();
    WAIT_LGKM0();
    PRIO1(); MFMAQ(3, 1, 1); PRIO0();
  }
  // ---- epilogue tile2
#pragma unroll
  for (int mf = 0; mf < 8; ++mf) {
    const int m0 = (bm + 16) * 256 + wm * 128 + mf * 16 + kg * 4;
#pragma unroll
    for (int nf = 0; nf < 4; ++nf) {
      const int n = bn * 256 + wn * 64 + nf * 16 + l16;
      const float bv = bias[n];
#pragma unroll
      for (int r = 0; r < 4; ++r)
        C[(size_t)(m0 + r) * N_DIM + n] = acc[mf][nf][r] + bv;
    }
  }
}

// ---------------- fallback: fused naive ----------------
__global__ __launch_bounds__(256) void naive_fused(const float* __restrict__ x,
                                                   const int* __restrict__ q,
                                                   const float* __restrict__ scales,
                                                   const float* __restrict__ bias,
                                                   float* __restrict__ out) {
  __shared__ float xs[K_DIM];
  const int m = blockIdx.y;
  const int n = blockIdx.x * 256 + threadIdx.x;
  for (int k = threadIdx.x; k < K_DIM; k += 256)
    xs[k] = x[(size_t)m * K_DIM + k];
  __syncthreads();

  const int4* q4 = reinterpret_cast<const int4*>(q) + (size_t)n * 512;
  float acc = 0.f, sc = 0.f;
  for (int c = 0; c < 512; ++c) {
    if ((c & 3) == 0) sc = scales[n * 128 + (c >> 2)];
    int4 v = q4[c];
    int b0 = v.x & 0xFF, b1 = v.y & 0xFF, b2 = v.z & 0xFF, b3 = v.w & 0xFF;
    int k = c * 8;
    acc += xs[k + 0] * fp4_to_f32((b0 >> 4) & 15) * sc;
    acc += xs[k + 1] * fp4_to_f32(b0 & 15) * sc;
    acc += xs[k + 2] * fp4_to_f32((b1 >> 4) & 15) * sc;
    acc += xs[k + 3] * fp4_to_f32(b1 & 15) * sc;
    acc += xs[k + 4] * fp4_to_f32((b2 >> 4) & 15) * sc;
    acc += xs[k + 5] * fp4_to_f32(b2 & 15) * sc;
    acc += xs[k + 6] * fp4_to_f32((b3 >> 4) & 15) * sc;
    acc += xs[k + 7] * fp4_to_f32(b3 & 15) * sc;
  }
  out[(size_t)m * N_DIM + n] = acc + bias[n];
}

// ---------------- launch ----------------
extern "C" void kernel_launch(void* const* d_in, const int* in_sizes, int n_in,
                              void* d_out, int out_size, void* d_ws, size_t ws_size,
                              hipStream_t stream) {
  const float* x    = (const float*)d_in[0];
  const int*   q    = (const int*)d_in[1];
  const float* sc   = (const float*)d_in[2];
  const float* bias = (const float*)d_in[3];
  float* out = (float*)d_out;

  const size_t xb_bytes = (size_t)M_DIM * K_DIM * 2;
  const size_t w_bytes  = (size_t)N_DIM * K_DIM * 2;

  if (ws_size >= xb_bytes + w_bytes) {
    uint32_t* xb = (uint32_t*)d_ws;
    uint32_t* W  = (uint32_t*)((char*)d_ws + xb_bytes);

    pre_all<<<2048 + 16384, 256, 0, stream>>>(q, sc, W, x, xb);
    gemm256_p2<<<dim3(256), 512, 0, stream>>>((const __bf16*)xb, (const __bf16*)W, bias, out);
  } else {
    dim3 grid(N_DIM / 256, M_DIM);
    naive_fused<<<grid, 256, 0, stream>>>(x, q, sc, bias, out);
  }
}

// Round 16
// 274.317 us; speedup vs baseline: 1.2740x; 1.2740x over previous
//
#include <hip/hip_runtime.h>
#include <hip/hip_bf16.h>
#include <stdint.h>

// y[b,s,o] = sum_k x[b,s,k] * W[o,k] + bias[o]
// W from packed FP4 (E2M1 nibbles in int32 bytes) * per-32 fp32 scales.
// M = 8192, N = 4096, K = 4096.
// r16 = r14 verbatim (best verified: 274.7 us total, GEMM 227.5 us,
// 0 LDS conflicts, MfmaUtil 54%). Closed lines: 32x32 MFMA (r10-r12,
// unexplained conflicts), 1-barrier/K-tile (r7, vmcnt drain), barrier
// removal (r8, race), B-frag dbuf (r15, VGPR spill via WRITE_SIZE +26MB).

#define M_DIM 8192
#define N_DIM 4096
#define K_DIM 4096

typedef __bf16 bf16x8 __attribute__((ext_vector_type(8)));
typedef float  f32x4  __attribute__((ext_vector_type(4)));
typedef int    i32x4  __attribute__((ext_vector_type(4)));
typedef float  f32x4v __attribute__((ext_vector_type(4)));

// ---------------- helpers ----------------

__device__ __forceinline__ uint16_t f32_to_bf16_rn(float f) {
  uint32_t u = __float_as_uint(f);
  uint32_t r = (u + 0x7FFFu + ((u >> 16) & 1u)) >> 16;
  return (uint16_t)r;
}
__device__ __forceinline__ uint32_t pack_bf16x2(float e0, float e1) {
  return (uint32_t)f32_to_bf16_rn(e0) | ((uint32_t)f32_to_bf16_rn(e1) << 16);
}
__device__ __forceinline__ float fp4_to_f32(int nib) {
  uint32_t e = (uint32_t)(nib >> 1) & 3u;
  uint32_t m = (uint32_t)nib & 1u;
  uint32_t s = (uint32_t)(nib >> 3) & 1u;
  uint32_t bits = e ? (((126u + e) << 23) | (m << 22)) : (m ? 0x3F000000u : 0u);
  bits |= s << 31;
  return __uint_as_float(bits);
}
__device__ __forceinline__ void gload_lds16(const void* g, void* lds) {
  __builtin_amdgcn_global_load_lds(
      (const __attribute__((address_space(1))) unsigned int*)g,
      (__attribute__((address_space(3))) unsigned int*)lds,
      16, 0, 0);
}

// ---------------- merged pre-kernel: dequant W + cvt x ----------------
// NT loads on x and q (read-once streams) keep L2/L3 for W/xb, which the
// GEMM re-reads immediately.
__global__ __launch_bounds__(256) void pre_all(const int* __restrict__ q,
                                               const float* __restrict__ scales,
                                               uint32_t* __restrict__ W,
                                               const float* __restrict__ x,
                                               uint32_t* __restrict__ xb) {
  const int bid = blockIdx.x;
  if (bid < 2048) {
    int b = bid * 256 + threadIdx.x;
    float sc = scales[b];
    const i32x4* q4 = reinterpret_cast<const i32x4*>(q) + (size_t)b * 4;
    i32x4* dst = reinterpret_cast<i32x4*>(W + (size_t)b * 16);
#pragma unroll
    for (int i = 0; i < 4; ++i) {
      i32x4 v = __builtin_nontemporal_load(q4 + i);
      int b0 = v[0] & 0xFF, b1 = v[1] & 0xFF, b2 = v[2] & 0xFF, b3 = v[3] & 0xFF;
      uint32_t p0 = pack_bf16x2(fp4_to_f32((b0 >> 4) & 15) * sc, fp4_to_f32(b0 & 15) * sc);
      uint32_t p1 = pack_bf16x2(fp4_to_f32((b1 >> 4) & 15) * sc, fp4_to_f32(b1 & 15) * sc);
      uint32_t p2 = pack_bf16x2(fp4_to_f32((b2 >> 4) & 15) * sc, fp4_to_f32(b2 & 15) * sc);
      uint32_t p3 = pack_bf16x2(fp4_to_f32((b3 >> 4) & 15) * sc, fp4_to_f32(b3 & 15) * sc);
      i32x4 o;
      o[0] = (int)p0; o[1] = (int)p1; o[2] = (int)p2; o[3] = (int)p3;
      dst[i] = o;
    }
  } else {
    size_t i = ((size_t)(bid - 2048) * 256 + threadIdx.x) * 8;
    f32x4v a = __builtin_nontemporal_load(reinterpret_cast<const f32x4v*>(x + i));
    f32x4v c = __builtin_nontemporal_load(reinterpret_cast<const f32x4v*>(x + i + 4));
    i32x4 o;
    o[0] = (int)pack_bf16x2(a[0], a[1]);
    o[1] = (int)pack_bf16x2(a[2], a[3]);
    o[2] = (int)pack_bf16x2(c[0], c[1]);
    o[3] = (int)pack_bf16x2(c[2], c[3]);
    *reinterpret_cast<i32x4*>(xb + i / 2) = o;
  }
}

// ---------------- GEMM: 256x256 8-phase, persistent 2-tile blocks ----------
// r5 schedule (register-pipelined, counted vmcnt/lgkm, 8 barriers/pair —
// P0/P4 barriers are REQUIRED: they order P0/P4's LDB(buf) reads against
// P1/P5's B-stage writes of the SAME buffer region; removing them raced
// (r8, absmax 129)).
//  - grid 256: each block does (bm,bn) then (bm+16,bn); tile2 K0/K1 staged
//    in tile1's peel slots; epilogue-1 stores drain under tile2 compute.

#define BUF0 0
#define BUF1 65536
#define A0OFF 0
#define A1OFF 16384
#define B0OFF 32768
#define B1OFF 49152
#define AH1 (128 * 4096)       // +128 rows (elements)

#define BARRIER()   asm volatile("s_barrier" ::: "memory")
#define WAIT_LGKM0() do { asm volatile("s_waitcnt lgkmcnt(0)" ::: "memory"); \
                          __builtin_amdgcn_sched_barrier(0); } while (0)
#define LGKM4()     do { asm volatile("s_waitcnt lgkmcnt(4)" ::: "memory"); \
                          __builtin_amdgcn_sched_barrier(0); } while (0)
#define WAIT_VM6()  asm volatile("s_waitcnt vmcnt(6)" ::: "memory")
#define WAIT_VM4()  asm volatile("s_waitcnt vmcnt(4)" ::: "memory")
#define WAIT_VM0()  asm volatile("s_waitcnt vmcnt(0)" ::: "memory")
#define PRIO1()     __builtin_amdgcn_s_setprio(1)
#define PRIO0()     __builtin_amdgcn_s_setprio(0)

#define LDA2(SET, CB, F) do {                                      \
    const uint32_t r0_ = a_rd + (F) * 2048;                        \
    const uint32_t r1_ = a_rd + ((F) + 1) * 2048;                  \
    aA[SET][0][0] = *(const bf16x8*)(smem + (CB) + r0_);           \
    aA[SET][0][1] = *(const bf16x8*)(smem + (CB) + (r0_ ^ 64));    \
    aA[SET][1][0] = *(const bf16x8*)(smem + (CB) + r1_);           \
    aA[SET][1][1] = *(const bf16x8*)(smem + (CB) + (r1_ ^ 64));    \
  } while (0)

#define LDB(CB) do {                                               \
    _Pragma("unroll")                                              \
    for (int nf_ = 0; nf_ < 4; ++nf_) {                            \
      const uint32_t r_ = b_rd + nf_ * 2048;                       \
      bfr[nf_][0] = *(const bf16x8*)(smem + (CB) + r_);            \
      bfr[nf_][1] = *(const bf16x8*)(smem + (CB) + (r_ ^ 64));     \
    }                                                              \
  } while (0)

#define MFMAQ(Q, SET) do {                                         \
    _Pragma("unroll")                                              \
    for (int nf_ = 0; nf_ < 4; ++nf_) {                            \
      _Pragma("unroll")                                            \
      for (int kk_ = 0; kk_ < 2; ++kk_) {                          \
        acc[2*(Q)][nf_] = __builtin_amdgcn_mfma_f32_16x16x32_bf16( \
            aA[SET][0][kk_], bfr[nf_][kk_], acc[2*(Q)][nf_], 0, 0, 0);   \
        acc[2*(Q)+1][nf_] = __builtin_amdgcn_mfma_f32_16x16x32_bf16(     \
            aA[SET][1][kk_], bfr[nf_][kk_], acc[2*(Q)+1][nf_], 0, 0, 0); \
      }                                                            \
    }                                                              \
  } while (0)

__device__ __forceinline__ void stage_half_tile(const __bf16* gsrc, char* lds_dst) {
  gload_lds16(gsrc, lds_dst);
  gload_lds16(gsrc + 64 * 4096, lds_dst + 8192);
}

// steady-state K-tile pair (E in buf0, O in buf1) — full 8 barriers
#define MAIN_PAIR(GA, kO, kE2, kO2)                                     \
  do {                                                                  \
    /* P0 */                                                            \
    WAIT_LGKM0(); LDB(BUF0); LDA2(1, BUF0, 2); LGKM4();                 \
    PRIO1(); MFMAQ(0, 0); PRIO0();                                      \
    stage_half_tile((GA) + AH1 + (kO), stw + BUF1 + A1OFF);             \
    BARRIER();                                                          \
    /* P1 */                                                            \
    WAIT_LGKM0(); LDA2(0, BUF0, 4);                                     \
    PRIO1(); MFMAQ(1, 1); PRIO0();                                      \
    stage_half_tile(gB + (kE2), stw + BUF0 + B0OFF);                    \
    BARRIER();                                                          \
    /* P2 */                                                            \
    WAIT_LGKM0(); LDA2(1, BUF0, 6);                                     \
    PRIO1(); MFMAQ(2, 0); PRIO0();                                      \
    stage_half_tile(gB + AH1 + (kE2), stw + BUF0 + B1OFF);              \
    WAIT_VM4();                                                         \
    BARRIER();                                                          \
    /* P3 */                                                            \
    WAIT_LGKM0(); LDA2(0, BUF1, 0);                                     \
    PRIO1(); MFMAQ(3, 1); PRIO0();                                      \
    stage_half_tile((GA) + (kE2), stw + BUF0 + A0OFF);                  \
    BARRIER();                                                          \
    /* P4 */                                                            \
    WAIT_LGKM0(); LDB(BUF1); LDA2(1, BUF1, 2); LGKM4();                 \
    PRIO1(); MFMAQ(0, 0); PRIO0();                                      \
    stage_half_tile((GA) + AH1 + (kE2), stw + BUF0 + A1OFF);            \
    BARRIER();                                                          \
    /* P5 */                                                            \
    WAIT_LGKM0(); LDA2(0, BUF1, 4);                                     \
    PRIO1(); MFMAQ(1, 1); PRIO0();                                      \
    stage_half_tile(gB + (kO2), stw + BUF1 + B0OFF);                    \
    BARRIER();                                                          \
    /* P6 */                                                            \
    WAIT_LGKM0(); LDA2(1, BUF1, 6);                                     \
    PRIO1(); MFMAQ(2, 0); PRIO0();                                      \
    stage_half_tile(gB + AH1 + (kO2), stw + BUF1 + B1OFF);              \
    stage_half_tile((GA) + (kO2),     stw + BUF1 + A0OFF);              \
    WAIT_VM6();                                                         \
    BARRIER();                                                          \
    /* P7 */                                                            \
    WAIT_LGKM0(); LDA2(0, BUF0, 0);                                     \
    PRIO1(); MFMAQ(3, 1); PRIO0();                                      \
    BARRIER();                                                          \
  } while (0)

__global__ __launch_bounds__(512, 2) void gemm256_p2(const __bf16* __restrict__ A,
                                                     const __bf16* __restrict__ B,
                                                     const float* __restrict__ bias,
                                                     float* __restrict__ C) {
  __shared__ __align__(16) char smem[131072];

  const int t    = threadIdx.x;          // 0..511
  const int wave = t >> 6;               // 0..7
  const int lane = t & 63;
  const int l16  = lane & 15;
  const int kg   = lane >> 4;            // 0..3
  const int wm   = wave >> 2;            // 0..1 (M half)
  const int wn   = wave & 3;             // 0..3 (N quarter)

  // XCD-aware bijective block swizzle (nwg = 256 = 8 x 32)
  const int orig = blockIdx.x;
  const int swz  = (orig & 7) * 32 + (orig >> 3);
  const int bn   = swz & 15;             // 16 bn (fastest)
  const int bm   = swz >> 4;             // 0..15 (tile2 uses bm+16)

  // staging source (pre-swizzled): thread t covers row t>>3 (+s*64),
  // chunk c8 = (t&7) ^ ((t>>3)&7)
  const int c8 = (t & 7) ^ ((t >> 3) & 7);
  const __bf16* gA  = A + ((size_t)(bm * 256 + (t >> 3))) * 4096 + c8 * 8;
  const __bf16* gA2 = gA + (size_t)16 * 256 * 4096;
  const __bf16* gB  = B + ((size_t)(bn * 256 + (t >> 3))) * 4096 + c8 * 8;
  char* stw = smem + wave * 1024;        // + lane*16 implicit in gload_lds

  // ds_read byte offsets (3-bit row swizzle): row = frag*16 + l16,
  // chunk bits [6:4] = kg ^ (l16&7); kk half via ^64 at use site
  const uint32_t ca = ((uint32_t)(kg ^ (l16 & 7))) << 4;
  const uint32_t a_rd = (uint32_t)(wm ? A1OFF : A0OFF) + (uint32_t)l16 * 128 + ca;
  const uint32_t b_rd = (uint32_t)(wn >= 2 ? B1OFF : B0OFF) +
                        (uint32_t)(wn & 1) * 8192 + (uint32_t)l16 * 128 + ca;

  f32x4 acc[8][4];
#pragma unroll
  for (int i = 0; i < 8; ++i)
#pragma unroll
    for (int j = 0; j < 4; ++j) acc[i][j] = (f32x4){0.f, 0.f, 0.f, 0.f};

  bf16x8 aA[2][2][2];   // [set][frag][kk]
  bf16x8 bfr[4][2];     // [nf][kk]

  // ---- prologue: tile0 K0 -> buf0 (8), K1 B + A0 -> buf1 (6)
  stage_half_tile(gA,            stw + BUF0 + A0OFF);
  stage_half_tile(gA + AH1,      stw + BUF0 + A1OFF);
  stage_half_tile(gB,            stw + BUF0 + B0OFF);
  stage_half_tile(gB + AH1,      stw + BUF0 + B1OFF);
  stage_half_tile(gB + 64,       stw + BUF1 + B0OFF);
  stage_half_tile(gB + AH1 + 64, stw + BUF1 + B1OFF);
  stage_half_tile(gA + 64,       stw + BUF1 + A0OFF);
  WAIT_VM6();
  BARRIER();
  LDA2(0, BUF0, 0);

  // ================= tile 1 (bm) =================
  for (int j = 0; j < 31; ++j) {
    const size_t kO  = (size_t)(2 * j + 1) * 64;
    const size_t kE2 = (size_t)(2 * j + 2) * 64;
    const size_t kO2 = (size_t)(2 * j + 3) * 64;
    MAIN_PAIR(gA, kO, kE2, kO2);
  }
  // ---- peel pair 31 (K62 buf0, K63 buf1) + stage tile2 K0/K1
  {
    const size_t kO = (size_t)63 * 64;
    WAIT_LGKM0(); LDB(BUF0); LDA2(1, BUF0, 2); LGKM4();
    PRIO1(); MFMAQ(0, 0); PRIO0();
    stage_half_tile(gA + AH1 + kO, stw + BUF1 + A1OFF);
    BARRIER();
    WAIT_LGKM0(); LDA2(0, BUF0, 4);
    PRIO1(); MFMAQ(1, 1); PRIO0();
    stage_half_tile(gB, stw + BUF0 + B0OFF);            // B0(t2 K0)
    BARRIER();
    WAIT_LGKM0(); LDA2(1, BUF0, 6);
    PRIO1(); MFMAQ(2, 0); PRIO0();
    stage_half_tile(gB + AH1, stw + BUF0 + B1OFF);      // B1(t2 K0)
    WAIT_VM4();            // certifies K63 -> buf1 fully landed
    BARRIER();
    WAIT_LGKM0(); LDA2(0, BUF1, 0);
    PRIO1(); MFMAQ(3, 1); PRIO0();
    stage_half_tile(gA2, stw + BUF0 + A0OFF);           // A0(t2 K0)
    BARRIER();
    WAIT_LGKM0(); LDB(BUF1); LDA2(1, BUF1, 2); LGKM4();
    PRIO1(); MFMAQ(0, 0); PRIO0();
    stage_half_tile(gA2 + AH1, stw + BUF0 + A1OFF);     // A1(t2 K0)
    BARRIER();
    WAIT_LGKM0(); LDA2(0, BUF1, 4);
    PRIO1(); MFMAQ(1, 1); PRIO0();
    stage_half_tile(gB + 64, stw + BUF1 + B0OFF);       // B0(t2 K1)
    BARRIER();
    WAIT_LGKM0(); LDA2(1, BUF1, 6);
    PRIO1(); MFMAQ(2, 0); PRIO0();
    stage_half_tile(gB + AH1 + 64, stw + BUF1 + B1OFF); // B1(t2 K1)
    BARRIER();
    WAIT_LGKM0();
    PRIO1(); MFMAQ(3, 1); PRIO0();
    stage_half_tile(gA2 + 64, stw + BUF1 + A0OFF);      // A0(t2 K1)
    WAIT_VM0();            // tile2 K0 + staged K1 parts landed
    BARRIER();
  }
  // ---- epilogue tile1: issue stores (drain under tile2 compute)
#pragma unroll
  for (int mf = 0; mf < 8; ++mf) {
    const int m0 = bm * 256 + wm * 128 + mf * 16 + kg * 4;
#pragma unroll
    for (int nf = 0; nf < 4; ++nf) {
      const int n = bn * 256 + wn * 64 + nf * 16 + l16;
      const float bv = bias[n];
#pragma unroll
      for (int r = 0; r < 4; ++r)
        C[(size_t)(m0 + r) * N_DIM + n] = acc[mf][nf][r] + bv;
    }
  }
#pragma unroll
  for (int i = 0; i < 8; ++i)
#pragma unroll
    for (int j = 0; j < 4; ++j) acc[i][j] = (f32x4){0.f, 0.f, 0.f, 0.f};
  LDA2(0, BUF0, 0);

  // ================= tile 2 (bm + 16) =================
  for (int j = 0; j < 31; ++j) {
    const size_t kO  = (size_t)(2 * j + 1) * 64;
    const size_t kE2 = (size_t)(2 * j + 2) * 64;
    const size_t kO2 = (size_t)(2 * j + 3) * 64;
    MAIN_PAIR(gA2, kO, kE2, kO2);
  }
  // ---- peel pair 31 (no further stages)
  {
    const size_t kO = (size_t)63 * 64;
    WAIT_LGKM0(); LDB(BUF0); LDA2(1, BUF0, 2); LGKM4();
    PRIO1(); MFMAQ(0, 0); PRIO0();
    stage_half_tile(gA2 + AH1 + kO, stw + BUF1 + A1OFF);
    BARRIER();
    WAIT_LGKM0(); LDA2(0, BUF0, 4);
    PRIO1(); MFMAQ(1, 1); PRIO0();
    BARRIER();
    WAIT_LGKM0(); LDA2(1, BUF0, 6);
    PRIO1(); MFMAQ(2, 0); PRIO0();
    WAIT_VM0();
    BARRIER();
    WAIT_LGKM0(); LDA2(0, BUF1, 0);
    PRIO1(); MFMAQ(3, 1); PRIO0();
    BARRIER();
    WAIT_LGKM0(); LDB(BUF1); LDA2(1, BUF1, 2); LGKM4();
    PRIO1(); MFMAQ(0, 0); PRIO0();
    BARRIER();
    WAIT_LGKM0(); LDA2(0, BUF1, 4);
    PRIO1(); MFMAQ(1, 1); PRIO0();
    BARRIER();
    WAIT_LGKM0(); LDA2(1, BUF1, 6);
    PRIO1(); MFMAQ(2, 0); PRIO0();
    BARRIER();
    WAIT_LGKM0();
    PRIO1(); MFMAQ(3, 1); PRIO0();
  }
  // ---- epilogue tile2
#pragma unroll
  for (int mf = 0; mf < 8; ++mf) {
    const int m0 = (bm + 16) * 256 + wm * 128 + mf * 16 + kg * 4;
#pragma unroll
    for (int nf = 0; nf < 4; ++nf) {
      const int n = bn * 256 + wn * 64 + nf * 16 + l16;
      const float bv = bias[n];
#pragma unroll
      for (int r = 0; r < 4; ++r)
        C[(size_t)(m0 + r) * N_DIM + n] = acc[mf][nf][r] + bv;
    }
  }
}

// ---------------- fallback: fused naive ----------------
__global__ __launch_bounds__(256) void naive_fused(const float* __restrict__ x,
                                                   const int* __restrict__ q,
                                                   const float* __restrict__ scales,
                                                   const float* __restrict__ bias,
                                                   float* __restrict__ out) {
  __shared__ float xs[K_DIM];
  const int m = blockIdx.y;
  const int n = blockIdx.x * 256 + threadIdx.x;
  for (int k = threadIdx.x; k < K_DIM; k += 256)
    xs[k] = x[(size_t)m * K_DIM + k];
  __syncthreads();

  const int4* q4 = reinterpret_cast<const int4*>(q) + (size_t)n * 512;
  float acc = 0.f, sc = 0.f;
  for (int c = 0; c < 512; ++c) {
    if ((c & 3) == 0) sc = scales[n * 128 + (c >> 2)];
    int4 v = q4[c];
    int b0 = v.x & 0xFF, b1 = v.y & 0xFF, b2 = v.z & 0xFF, b3 = v.w & 0xFF;
    int k = c * 8;
    acc += xs[k + 0] * fp4_to_f32((b0 >> 4) & 15) * sc;
    acc += xs[k + 1] * fp4_to_f32(b0 & 15) * sc;
    acc += xs[k + 2] * fp4_to_f32((b1 >> 4) & 15) * sc;
    acc += xs[k + 3] * fp4_to_f32(b1 & 15) * sc;
    acc += xs[k + 4] * fp4_to_f32((b2 >> 4) & 15) * sc;
    acc += xs[k + 5] * fp4_to_f32(b2 & 15) * sc;
    acc += xs[k + 6] * fp4_to_f32((b3 >> 4) & 15) * sc;
    acc += xs[k + 7] * fp4_to_f32(b3 & 15) * sc;
  }
  out[(size_t)m * N_DIM + n] = acc + bias[n];
}

// ---------------- launch ----------------
extern "C" void kernel_launch(void* const* d_in, const int* in_sizes, int n_in,
                              void* d_out, int out_size, void* d_ws, size_t ws_size,
                              hipStream_t stream) {
  const float* x    = (const float*)d_in[0];
  const int*   q    = (const int*)d_in[1];
  const float* sc   = (const float*)d_in[2];
  const float* bias = (const float*)d_in[3];
  float* out = (float*)d_out;

  const size_t xb_bytes = (size_t)M_DIM * K_DIM * 2;
  const size_t w_bytes  = (size_t)N_DIM * K_DIM * 2;

  if (ws_size >= xb_bytes + w_bytes) {
    uint32_t* xb = (uint32_t*)d_ws;
    uint32_t* W  = (uint32_t*)((char*)d_ws + xb_bytes);

    pre_all<<<2048 + 16384, 256, 0, stream>>>(q, sc, W, x, xb);
    gemm256_p2<<<dim3(256), 512, 0, stream>>>((const __bf16*)xb, (const __bf16*)W, bias, out);
  } else {
    dim3 grid(N_DIM / 256, M_DIM);
    naive_fused<<<grid, 256, 0, stream>>>(x, q, sc, bias, out);
  }
}